// Round 8
// baseline (415.550 us; speedup 1.0000x reference)
//
#include <hip/hip_runtime.h>
#include <hip/hip_bf16.h>

// SelfAttention: B=4, S=2048, E=1024, fp32 in/out, bf16 internal compute.
// Y[b,j,d] = sum_i softmax_i(Q_j.K_i / sqrt(S)) * V[i,d]
//
// R8: algebraic K-elimination. Q_j.K_i = X_j (Wq^T Wk) X_i^T + u_j + w_i + c
// with u = X.(Wq^T bk), w = X.(Wk^T bq), c = bq.bk. So one projection
// T = X.M replaces Q AND K (-17.2 GF of 120.3). Pipeline:
//   cvt (X, Wv plain bf16; Wq,Wk TRANSPOSED bf16; zero l)
//   aux (Mt[f][e] = sum_a Wkt[f][a] Wqt[e][a], 64-blk GEMM; g1,g2,c)
//   tv  (T = X.M -> d_out; V -> Vt transposed; + u,w matvec blocks)
//   scores (P = exp((T.X^T + u_j + w_i)*scale), row-sum atomics into l)
//   y   (Y = P.Vt^T / l)
// K-loop unchanged (BK=64, XOR-swizzle, global_load_lds, 0 bank conflicts).

typedef __bf16 bf16x8 __attribute__((ext_vector_type(8)));
typedef float  f32x4  __attribute__((ext_vector_type(4)));

__device__ __forceinline__ unsigned short f2bf(float f) {
    unsigned int u = __float_as_uint(f);
    u = (u + 0x7FFFu + ((u >> 16) & 1u)) >> 16;   // round-to-nearest-even
    return (unsigned short)u;
}

__device__ __forceinline__ float wave_reduce(float s) {
#pragma unroll
    for (int o = 32; o; o >>= 1) s += __shfl_xor(s, o, 64);
    return s;
}

// dot of 8 bf16 (as uint4) with 8 fp32 (two float4)
__device__ __forceinline__ float dot8(uint4 xv, float4 a, float4 b) {
    bf16x8 x = __builtin_bit_cast(bf16x8, xv);
    return (float)x[0]*a.x + (float)x[1]*a.y + (float)x[2]*a.z + (float)x[3]*a.w
         + (float)x[4]*b.x + (float)x[5]*b.y + (float)x[6]*b.z + (float)x[7]*b.w;
}

// blocks [0,8192): X cvt. [8192,9216): Wv cvt. [9216,9728): Wq/Wk transpose-cvt.
__global__ __launch_bounds__(256)
void cvt_all(const float* __restrict__ X,  const float* __restrict__ Wq,
             const float* __restrict__ Wk, const float* __restrict__ Wv,
             unsigned short* __restrict__ Xb,  unsigned short* __restrict__ Wqt,
             unsigned short* __restrict__ Wkt, unsigned short* __restrict__ Wvb,
             float* __restrict__ l) {
    __shared__ unsigned short tile[64 * 72];
    const int blk = blockIdx.x;
    const int t = threadIdx.x;

    if (blk < 8192) {                                // X: 2M float4
        long i = (long)blk * 256 + t;
        if (i < 8192) l[i] = 0.0f;
        float4 v = reinterpret_cast<const float4*>(X)[i];
        ushort4 o; o.x = f2bf(v.x); o.y = f2bf(v.y); o.z = f2bf(v.z); o.w = f2bf(v.w);
        reinterpret_cast<ushort4*>(Xb)[i] = o;
    } else if (blk < 9216) {                         // Wv: 256K float4
        long i = (long)(blk - 8192) * 256 + t;
        float4 v = reinterpret_cast<const float4*>(Wv)[i];
        ushort4 o; o.x = f2bf(v.x); o.y = f2bf(v.y); o.z = f2bf(v.z); o.w = f2bf(v.w);
        reinterpret_cast<ushort4*>(Wvb)[i] = o;
    } else {                                         // transpose 64x64 tiles
        const int tt  = blk - 9216;
        const int mat = tt >> 8;                     // 0=Wq, 1=Wk
        const int tl  = tt & 255;
        const int tr  = tl >> 4;                     // tile row (a-dim)
        const int tc  = tl & 15;                     // tile col (e-dim)
        const float* src = mat ? Wk : Wq;
        unsigned short* dst = mat ? Wkt : Wqt;
        const int r  = t >> 2;                       // 0..63 (input row a)
        const int c4 = t & 3;
#pragma unroll
        for (int it = 0; it < 4; ++it) {
            const int cc = c4 + it * 4;              // float4 col 0..15
            float4 v = *reinterpret_cast<const float4*>(
                src + (long)(tr * 64 + r) * 1024 + tc * 64 + cc * 4);
            tile[(cc * 4 + 0) * 72 + r] = f2bf(v.x);
            tile[(cc * 4 + 1) * 72 + r] = f2bf(v.y);
            tile[(cc * 4 + 2) * 72 + r] = f2bf(v.z);
            tile[(cc * 4 + 3) * 72 + r] = f2bf(v.w);
        }
        __syncthreads();
        const int rp = t >> 2;                       // output row (e-local)
#pragma unroll
        for (int it = 0; it < 2; ++it) {
            const int ch = (t & 3) + it * 4;         // ushort8 chunk 0..7
            *reinterpret_cast<uint4*>(dst + (long)(tc * 64 + rp) * 1024 + tr * 64 + ch * 8)
                = *reinterpret_cast<const uint4*>(&tile[rp * 72 + ch * 8]);
        }
    }
}

// ---- shared K-loop (R3 structure) ----
#define GEMM_DECLS                                                      \
    const int t    = threadIdx.x;                                       \
    const int wave = t >> 6;                                            \
    const int lane = t & 63;                                            \
    const int quad = lane >> 4;                                         \
    const int lr   = lane & 15;                                         \
    const int wm   = (wave >> 1) * 64;                                  \
    const int wn   = (wave & 1) * 64;                                   \
    const int sx   = lr & 7;                                            \
    const int lrow = lane >> 3;                                         \
    const int gch  = ((lane & 7) ^ (lrow & 7)) * 8;

#define GEMM_KLOOP(Aptr, Bptr, LDA, LDB)                                \
    for (int k0 = 0; k0 < K; k0 += 64) {                                \
        _Pragma("unroll")                                               \
        for (int r = 0; r < 4; ++r) {                                   \
            const int rowb = wave * 8 + r * 32;                         \
            const int row  = rowb + lrow;                               \
            const long goffA = (long)(m0 + row) * (LDA) + k0 + gch;     \
            const long goffB = (long)(n0 + row) * (LDB) + k0 + gch;     \
            __builtin_amdgcn_global_load_lds(                           \
                (const __attribute__((address_space(1))) void*)((Aptr) + goffA), \
                (__attribute__((address_space(3))) void*)(&lsA[rowb * 64]), 16, 0, 0); \
            __builtin_amdgcn_global_load_lds(                           \
                (const __attribute__((address_space(1))) void*)((Bptr) + goffB), \
                (__attribute__((address_space(3))) void*)(&lsB[rowb * 64]), 16, 0, 0); \
        }                                                               \
        __syncthreads();                                                \
        _Pragma("unroll")                                               \
        for (int h = 0; h < 2; ++h) {                                   \
            const int cp = ((h * 4 + quad) ^ sx) * 8;                   \
            bf16x8 af[4], bfr[4];                                       \
            _Pragma("unroll")                                           \
            for (int i = 0; i < 4; ++i) {                               \
                af[i]  = __builtin_bit_cast(bf16x8,                     \
                          *reinterpret_cast<const uint4*>(&lsA[(wm + i * 16 + lr) * 64 + cp])); \
                bfr[i] = __builtin_bit_cast(bf16x8,                     \
                          *reinterpret_cast<const uint4*>(&lsB[(wn + i * 16 + lr) * 64 + cp])); \
            }                                                           \
            _Pragma("unroll")                                           \
            for (int i = 0; i < 4; ++i)                                 \
                _Pragma("unroll")                                       \
                for (int j = 0; j < 4; ++j)                             \
                    acc[i][j] = __builtin_amdgcn_mfma_f32_16x16x32_bf16(af[i], bfr[j], acc[i][j], 0, 0, 0); \
        }                                                               \
        __syncthreads();                                                \
    }

// aux: blocks 0..63: Mt[f][e] = sum_a Wkt[f][a]*Wqt[e][a] (bf16 out).
// block 64: g1[e] = sum_a Wqt[e][a]*bk[a]. block 65: g2[f] + c = bq.bk.
__global__ __launch_bounds__(256, 2)
void aux_k(const unsigned short* __restrict__ Wkt,
           const unsigned short* __restrict__ Wqt,
           const float* __restrict__ bq, const float* __restrict__ bk,
           unsigned short* __restrict__ Mt,
           float* __restrict__ g1, float* __restrict__ g2,
           float* __restrict__ cbuf)
{
    __shared__ unsigned short lsA[128 * 64];
    __shared__ unsigned short lsB[128 * 64];
    const int blk = blockIdx.x;

    if (blk < 64) {
        const int m0 = (blk >> 3) * 128;   // f
        const int n0 = (blk & 7) * 128;    // e
        const int K = 1024;
        GEMM_DECLS
        f32x4 acc[4][4] = {};
        GEMM_KLOOP(Wkt, Wqt, 1024, 1024)
#pragma unroll
        for (int j = 0; j < 4; ++j) {
            const int n = n0 + wn + j * 16 + lr;
#pragma unroll
            for (int i = 0; i < 4; ++i) {
                const int mbase = m0 + wm + i * 16 + quad * 4;
#pragma unroll
                for (int r = 0; r < 4; ++r)
                    Mt[(long)(mbase + r) * 1024 + n] = f2bf(acc[i][j][r]);
            }
        }
        return;
    }

    const int t = threadIdx.x;
    const int wv = t >> 6, ln = t & 63;
    const unsigned short* W = (blk == 64) ? Wqt : Wkt;
    const float* bvec       = (blk == 64) ? bk  : bq;
    float* gout             = (blk == 64) ? g1  : g2;
    const float4* bf = reinterpret_cast<const float4*>(bvec);
    float4 p0 = bf[ln * 2], p1 = bf[ln * 2 + 1];
    float4 p2 = bf[128 + ln * 2], p3 = bf[128 + ln * 2 + 1];
    for (int rr = 0; rr < 256; ++rr) {
        const int e = wv * 256 + rr;
        uint4 x0 = *reinterpret_cast<const uint4*>(W + (long)e * 1024 + ln * 8);
        uint4 x1 = *reinterpret_cast<const uint4*>(W + (long)e * 1024 + 512 + ln * 8);
        float s = wave_reduce(dot8(x0, p0, p1) + dot8(x1, p2, p3));
        if (ln == 0) gout[e] = s;
    }
    if (blk == 65 && wv == 0) {
        float s = 0.f;
        for (int a = ln; a < 1024; a += 64) s += bq[a] * bk[a];
        s = wave_reduce(s);
        if (ln == 0) *cbuf = s;
    }
}

// tv: ids [0,1024): GEMM z=0 -> T = X.M (bf16, d_out), z=1 -> V -> Vt transposed.
// ids [1024,1056): u/w matvec waves (u = X.g1 ; w = X.g2 + c).
__global__ __launch_bounds__(256, 2)
void gemm_tv(const unsigned short* __restrict__ Xb,
             const unsigned short* __restrict__ Mt,
             const unsigned short* __restrict__ Wvb,
             const float* __restrict__ bv_,
             const float* __restrict__ g1, const float* __restrict__ g2,
             const float* __restrict__ cbuf,
             unsigned short* __restrict__ T, unsigned short* __restrict__ Vt,
             float* __restrict__ u, float* __restrict__ w)
{
    __shared__ unsigned short lsA[128 * 64];
    __shared__ unsigned short lsB[128 * 64];
    const int id = blockIdx.x;

    if (id >= 1024) {                         // u/w matvec
        const int t = threadIdx.x;
        const int wave = t >> 6, lane = t & 63;
        const int wid = (id - 1024) * 4 + wave;          // 0..127
        const float* g = (wid < 64) ? g1 : g2;
        const float4* gf = reinterpret_cast<const float4*>(g);
        float4 q0 = gf[lane * 2], q1 = gf[lane * 2 + 1];
        float4 q2 = gf[128 + lane * 2], q3 = gf[128 + lane * 2 + 1];
        const float cadd = (wid < 64) ? 0.0f : *cbuf;
        for (int rr = 0; rr < 128; ++rr) {
            const int row  = wid * 128 + rr;             // 0..16383
            const int xrow = row & 8191;
            uint4 x0 = *reinterpret_cast<const uint4*>(Xb + (long)xrow * 1024 + lane * 8);
            uint4 x1 = *reinterpret_cast<const uint4*>(Xb + (long)xrow * 1024 + 512 + lane * 8);
            float s = wave_reduce(dot8(x0, q0, q1) + dot8(x1, q2, q3));
            if (lane == 0) {
                if (row < 8192) u[row] = s;
                else            w[row - 8192] = s + cadd;
            }
        }
        return;
    }

    const int g   = id & 7;
    const int jj  = id >> 3;
    const int xx  = jj & 7;
    const int yin = (jj >> 3) & 7;
    const int z   = jj >> 6;                  // 0=T, 1=V

    const unsigned short* B = (z == 0) ? Mt : Wvb;
    const int n0 = xx * 128;
    const int m0 = (g * 8 + yin) * 128;
    const int K = 1024;

    GEMM_DECLS
    f32x4 acc[4][4] = {};
    GEMM_KLOOP(Xb, B, 1024, 1024)

#pragma unroll
    for (int j = 0; j < 4; ++j) {
        const int n = n0 + wn + j * 16 + lr;
        const float bvv = (z == 1) ? bv_[n] : 0.0f;
#pragma unroll
        for (int i = 0; i < 4; ++i) {
            const int mbase = m0 + wm + i * 16 + quad * 4;
            if (z == 0) {
#pragma unroll
                for (int r = 0; r < 4; ++r)
                    T[(long)(mbase + r) * 1024 + n] = f2bf(acc[i][j][r]);
            } else {
                ushort4 o;
                o.x = f2bf(acc[i][j][0] + bvv);
                o.y = f2bf(acc[i][j][1] + bvv);
                o.z = f2bf(acc[i][j][2] + bvv);
                o.w = f2bf(acc[i][j][3] + bvv);
                long boff = (long)(mbase >> 11) * (1024L * 2048) + (long)n * 2048 + (mbase & 2047);
                *reinterpret_cast<ushort4*>(Vt + boff) = o;
            }
        }
    }
}

// Scores: P[b][j][i] = exp((T_j.X_i + u_j + w_i)*scale) bf16, l atomics.
__global__ __launch_bounds__(256, 2)
void gemm_scores(const unsigned short* __restrict__ T,
                 const unsigned short* __restrict__ Xb,
                 const float* __restrict__ u, const float* __restrict__ w,
                 unsigned short* __restrict__ P, float* __restrict__ l,
                 float scale)
{
    __shared__ unsigned short lsA[128 * 64];
    __shared__ unsigned short lsB[128 * 64];

    const int id  = blockIdx.x;
    const int g   = id & 7;
    const int uu  = id >> 3;
    const int bz  = g >> 1;
    const int mh  = g & 1;
    const int yin = uu & 7;
    const int xx  = uu >> 3;                 // 0..15

    const unsigned short* A = T  + (long)bz * 2048 * 1024;
    const unsigned short* B = Xb + (long)bz * 2048 * 1024;
    unsigned short* Pb = P + (long)bz * 2048 * 2048;
    float* lb = l + bz * 2048;

    const int n0 = xx * 128;
    const int m0 = (mh * 8 + yin) * 128;
    const int K = 1024;

    GEMM_DECLS
    f32x4 acc[4][4] = {};
    GEMM_KLOOP(A, B, 1024, 1024)

    float wn4[4];
#pragma unroll
    for (int j = 0; j < 4; ++j)
        wn4[j] = w[bz * 2048 + n0 + wn + j * 16 + lr];

#pragma unroll
    for (int i = 0; i < 4; ++i) {
#pragma unroll
        for (int r = 0; r < 4; ++r) {
            const int m = m0 + wm + i * 16 + quad * 4 + r;
            const float um = u[bz * 2048 + m];
            float psum = 0.0f;
#pragma unroll
            for (int j = 0; j < 4; ++j) {
                const float p = __expf((acc[i][j][r] + um + wn4[j]) * scale);
                psum += p;
                const int n = n0 + wn + j * 16 + lr;
                Pb[(long)m * 2048 + n] = f2bf(p);
            }
#pragma unroll
            for (int o = 1; o < 16; o <<= 1) psum += __shfl_xor(psum, o, 64);
            if (lr == 0) atomicAdd(&lb[m], psum);
        }
    }
}

// Y[b][j][d] = (1/l[b,j]) * sum_i P[b][j][i]*Vt[b][d][i] -> fp32 out.
__global__ __launch_bounds__(256, 2)
void gemm_y(const unsigned short* __restrict__ P,
            const unsigned short* __restrict__ Vt,
            const float* __restrict__ l, float* __restrict__ out)
{
    __shared__ unsigned short lsA[128 * 64];
    __shared__ unsigned short lsB[128 * 64];

    const int id  = blockIdx.x;
    const int g   = id & 7;
    const int uu  = id >> 3;
    const int bz  = g >> 1;
    const int mh  = g & 1;
    const int yin = uu & 7;
    const int xx  = uu >> 3;                 // 0..7

    const unsigned short* A = P  + (long)bz * 2048 * 2048;
    const unsigned short* B = Vt + (long)bz * 1024 * 2048;
    const float* lb = l + bz * 2048;
    float* C = out + (long)bz * 2048 * 1024;

    const int n0 = xx * 128;
    const int m0 = (mh * 8 + yin) * 128;
    const int K = 2048;

    GEMM_DECLS
    f32x4 acc[4][4] = {};
    GEMM_KLOOP(A, B, 2048, 2048)

    float linv[4][4];
#pragma unroll
    for (int i = 0; i < 4; ++i)
#pragma unroll
        for (int r = 0; r < 4; ++r)
            linv[i][r] = 1.0f / lb[m0 + wm + i * 16 + quad * 4 + r];

#pragma unroll
    for (int j = 0; j < 4; ++j) {
        const int n = n0 + wn + j * 16 + lr;
#pragma unroll
        for (int i = 0; i < 4; ++i) {
            const int mbase = m0 + wm + i * 16 + quad * 4;
#pragma unroll
            for (int r = 0; r < 4; ++r)
                C[(long)(mbase + r) * 1024 + n] = acc[i][j][r] * linv[i][r];
        }
    }
}

extern "C" void kernel_launch(void* const* d_in, const int* in_sizes, int n_in,
                              void* d_out, int out_size, void* d_ws, size_t ws_size,
                              hipStream_t stream) {
    const float* X  = (const float*)d_in[0];
    const float* Wk = (const float*)d_in[1];
    const float* bk = (const float*)d_in[2];
    const float* Wq = (const float*)d_in[3];
    const float* bq = (const float*)d_in[4];
    const float* Wv = (const float*)d_in[5];
    const float* bv = (const float*)d_in[6];
    float* out = (float*)d_out;

    const size_t MB = 1024 * 1024;
    if (ws_size < 80 * MB) return;   // visible failure instead of OOB corruption

    char* ws = (char*)d_ws;
    unsigned short* Vt  = (unsigned short*)(ws);            // 16 MiB
    unsigned short* P   = (unsigned short*)(ws + 16 * MB);  // 32 MiB
    unsigned short* Xbf = (unsigned short*)(ws + 48 * MB);  // 16 MiB (no P overlap!)
    unsigned short* Wqt = (unsigned short*)(ws + 64 * MB);  // 2 MiB (transposed)
    unsigned short* Wkt = (unsigned short*)(ws + 66 * MB);  // 2 MiB (transposed)
    unsigned short* Wvb = (unsigned short*)(ws + 68 * MB);  // 2 MiB
    unsigned short* Mt  = (unsigned short*)(ws + 70 * MB);  // 2 MiB
    float* l    = (float*)(ws + 72 * MB);                   // 32 KiB
    float* u    = (float*)(ws + 72 * MB + 32 * 1024);       // 32 KiB
    float* w    = (float*)(ws + 72 * MB + 64 * 1024);       // 32 KiB
    float* g1   = (float*)(ws + 72 * MB + 96 * 1024);       // 4 KiB
    float* g2   = (float*)(ws + 72 * MB + 100 * 1024);      // 4 KiB
    float* cbuf = (float*)(ws + 72 * MB + 104 * 1024);      // 4 B
    // T bf16 (16 MiB) lives in d_out until gemm_y overwrites it
    unsigned short* T = (unsigned short*)d_out;

    dim3 blk(256);

    // 1) cvt: X, Wv plain; Wq/Wk transposed; zero l
    cvt_all<<<9728, blk, 0, stream>>>(X, Wq, Wk, Wv, Xbf, Wqt, Wkt, Wvb, l);

    // 2) Mt = Wq^T.Wk (stored [f][e]) + g1,g2,c
    aux_k<<<66, blk, 0, stream>>>(Wkt, Wqt, bq, bk, Mt, g1, g2, cbuf);

    // 3) T = X.M, V -> Vt; u,w matvecs
    gemm_tv<<<1056, blk, 0, stream>>>(Xbf, Mt, Wvb, bv, g1, g2, cbuf, T, Vt, u, w);

    // 4) scores + exp + row-sum atomics
    gemm_scores<<<1024, blk, 0, stream>>>(T, Xbf, u, w, P, l, 0.022097086912079608f);

    // 5) Y = (P @ Vt^T) / l
    gemm_y<<<512, blk, 0, stream>>>(P, Vt, l, out);
}

// Round 9
// 290.784 us; speedup vs baseline: 1.4291x; 1.4291x over previous
//
#include <hip/hip_runtime.h>
#include <hip/hip_bf16.h>

// SelfAttention: B=4, S=2048, E=1024, fp32 in/out, bf16 internal compute.
// Y[b,j,d] = sum_i softmax_i(Q_j.K_i / sqrt(S)) * V[i,d]
//
// R9 = R8's algebraic K-elimination with the parallelism bug fixed:
//   Q_j.K_i = X_j (Wq^T Wk) X_i^T + u_j + w_i + c
//   - g1/g2/c now computed in cvt_all (9 extra blocks, fp32 column dots)
//     instead of 2 serial blocks in aux_k (R8: 134us @ 0.6% occupancy).
//   - aux_k reduced to the 64-block Mt GEMM.
//   - u/w matvecs widened to 64 blocks (256 waves x 64 rows).
// K-loop unchanged (BK=64, XOR-swizzle, global_load_lds, 0 bank conflicts).

typedef __bf16 bf16x8 __attribute__((ext_vector_type(8)));
typedef float  f32x4  __attribute__((ext_vector_type(4)));

__device__ __forceinline__ unsigned short f2bf(float f) {
    unsigned int u = __float_as_uint(f);
    u = (u + 0x7FFFu + ((u >> 16) & 1u)) >> 16;   // round-to-nearest-even
    return (unsigned short)u;
}

__device__ __forceinline__ float wave_reduce(float s) {
#pragma unroll
    for (int o = 32; o; o >>= 1) s += __shfl_xor(s, o, 64);
    return s;
}

// dot of 8 bf16 (as uint4) with 8 fp32 (two float4)
__device__ __forceinline__ float dot8(uint4 xv, float4 a, float4 b) {
    bf16x8 x = __builtin_bit_cast(bf16x8, xv);
    return (float)x[0]*a.x + (float)x[1]*a.y + (float)x[2]*a.z + (float)x[3]*a.w
         + (float)x[4]*b.x + (float)x[5]*b.y + (float)x[6]*b.z + (float)x[7]*b.w;
}

// blocks [0,8192): X cvt. [8192,9216): Wv cvt. [9216,9728): Wq/Wk transpose.
// [9728,9736): g1/g2 column dots (fp32). 9736: c = bq.bk.
__global__ __launch_bounds__(256)
void cvt_all(const float* __restrict__ X,  const float* __restrict__ Wq,
             const float* __restrict__ Wk, const float* __restrict__ Wv,
             const float* __restrict__ bq, const float* __restrict__ bk,
             unsigned short* __restrict__ Xb,  unsigned short* __restrict__ Wqt,
             unsigned short* __restrict__ Wkt, unsigned short* __restrict__ Wvb,
             float* __restrict__ g1, float* __restrict__ g2,
             float* __restrict__ cbuf, float* __restrict__ l) {
    __shared__ unsigned short tile[64 * 72];
    const int blk = blockIdx.x;
    const int t = threadIdx.x;

    if (blk < 8192) {                                // X: 2M float4
        long i = (long)blk * 256 + t;
        if (i < 8192) l[i] = 0.0f;
        float4 v = reinterpret_cast<const float4*>(X)[i];
        ushort4 o; o.x = f2bf(v.x); o.y = f2bf(v.y); o.z = f2bf(v.z); o.w = f2bf(v.w);
        reinterpret_cast<ushort4*>(Xb)[i] = o;
    } else if (blk < 9216) {                         // Wv: 256K float4
        long i = (long)(blk - 8192) * 256 + t;
        float4 v = reinterpret_cast<const float4*>(Wv)[i];
        ushort4 o; o.x = f2bf(v.x); o.y = f2bf(v.y); o.z = f2bf(v.z); o.w = f2bf(v.w);
        reinterpret_cast<ushort4*>(Wvb)[i] = o;
    } else if (blk < 9728) {                         // transpose 64x64 tiles
        const int tt  = blk - 9216;
        const int mat = tt >> 8;                     // 0=Wq, 1=Wk
        const int tl  = tt & 255;
        const int tr  = tl >> 4;                     // tile row (a-dim)
        const int tc  = tl & 15;                     // tile col (e-dim)
        const float* src = mat ? Wk : Wq;
        unsigned short* dst = mat ? Wkt : Wqt;
        const int r  = t >> 2;                       // 0..63 (input row a)
        const int c4 = t & 3;
#pragma unroll
        for (int it = 0; it < 4; ++it) {
            const int cc = c4 + it * 4;              // float4 col 0..15
            float4 v = *reinterpret_cast<const float4*>(
                src + (long)(tr * 64 + r) * 1024 + tc * 64 + cc * 4);
            tile[(cc * 4 + 0) * 72 + r] = f2bf(v.x);
            tile[(cc * 4 + 1) * 72 + r] = f2bf(v.y);
            tile[(cc * 4 + 2) * 72 + r] = f2bf(v.z);
            tile[(cc * 4 + 3) * 72 + r] = f2bf(v.w);
        }
        __syncthreads();
        const int rp = t >> 2;                       // output row (e-local)
#pragma unroll
        for (int it = 0; it < 2; ++it) {
            const int ch = (t & 3) + it * 4;         // ushort8 chunk 0..7
            *reinterpret_cast<uint4*>(dst + (long)(tc * 64 + rp) * 1024 + tr * 64 + ch * 8)
                = *reinterpret_cast<const uint4*>(&tile[rp * 72 + ch * 8]);
        }
    } else if (blk < 9736) {                         // g1[e], g2[e] column dots
        const int gb  = blk - 9728;                  // 0..7
        const int mat = gb >> 2;                     // 0 -> g1(Wq,bk), 1 -> g2(Wk,bq)
        const int e   = (gb & 3) * 256 + t;
        const float* W    = mat ? Wk : Wq;
        const float* bvec = mat ? bq : bk;
        float s0 = 0.f, s1 = 0.f, s2 = 0.f, s3 = 0.f;
        for (int a = 0; a < 1024; a += 4) {
            s0 += W[(long)(a + 0) * 1024 + e] * bvec[a + 0];
            s1 += W[(long)(a + 1) * 1024 + e] * bvec[a + 1];
            s2 += W[(long)(a + 2) * 1024 + e] * bvec[a + 2];
            s3 += W[(long)(a + 3) * 1024 + e] * bvec[a + 3];
        }
        (mat ? g2 : g1)[e] = (s0 + s1) + (s2 + s3);
    } else {                                         // c = bq.bk
        if (t < 64) {
            float s = 0.f;
            for (int a = t; a < 1024; a += 64) s += bq[a] * bk[a];
            s = wave_reduce(s);
            if (t == 0) *cbuf = s;
        }
    }
}

// ---- shared K-loop (R3 structure) ----
#define GEMM_DECLS                                                      \
    const int t    = threadIdx.x;                                       \
    const int wave = t >> 6;                                            \
    const int lane = t & 63;                                            \
    const int quad = lane >> 4;                                         \
    const int lr   = lane & 15;                                         \
    const int wm   = (wave >> 1) * 64;                                  \
    const int wn   = (wave & 1) * 64;                                   \
    const int sx   = lr & 7;                                            \
    const int lrow = lane >> 3;                                         \
    const int gch  = ((lane & 7) ^ (lrow & 7)) * 8;

#define GEMM_KLOOP(Aptr, Bptr, LDA, LDB)                                \
    for (int k0 = 0; k0 < K; k0 += 64) {                                \
        _Pragma("unroll")                                               \
        for (int r = 0; r < 4; ++r) {                                   \
            const int rowb = wave * 8 + r * 32;                         \
            const int row  = rowb + lrow;                               \
            const long goffA = (long)(m0 + row) * (LDA) + k0 + gch;     \
            const long goffB = (long)(n0 + row) * (LDB) + k0 + gch;     \
            __builtin_amdgcn_global_load_lds(                           \
                (const __attribute__((address_space(1))) void*)((Aptr) + goffA), \
                (__attribute__((address_space(3))) void*)(&lsA[rowb * 64]), 16, 0, 0); \
            __builtin_amdgcn_global_load_lds(                           \
                (const __attribute__((address_space(1))) void*)((Bptr) + goffB), \
                (__attribute__((address_space(3))) void*)(&lsB[rowb * 64]), 16, 0, 0); \
        }                                                               \
        __syncthreads();                                                \
        _Pragma("unroll")                                               \
        for (int h = 0; h < 2; ++h) {                                   \
            const int cp = ((h * 4 + quad) ^ sx) * 8;                   \
            bf16x8 af[4], bfr[4];                                       \
            _Pragma("unroll")                                           \
            for (int i = 0; i < 4; ++i) {                               \
                af[i]  = __builtin_bit_cast(bf16x8,                     \
                          *reinterpret_cast<const uint4*>(&lsA[(wm + i * 16 + lr) * 64 + cp])); \
                bfr[i] = __builtin_bit_cast(bf16x8,                     \
                          *reinterpret_cast<const uint4*>(&lsB[(wn + i * 16 + lr) * 64 + cp])); \
            }                                                           \
            _Pragma("unroll")                                           \
            for (int i = 0; i < 4; ++i)                                 \
                _Pragma("unroll")                                       \
                for (int j = 0; j < 4; ++j)                             \
                    acc[i][j] = __builtin_amdgcn_mfma_f32_16x16x32_bf16(af[i], bfr[j], acc[i][j], 0, 0, 0); \
        }                                                               \
        __syncthreads();                                                \
    }

// Mt[f][e] = sum_a Wkt[f][a]*Wqt[e][a] (bf16 out). 64 blocks.
__global__ __launch_bounds__(256, 2)
void aux_k(const unsigned short* __restrict__ Wkt,
           const unsigned short* __restrict__ Wqt,
           unsigned short* __restrict__ Mt)
{
    __shared__ unsigned short lsA[128 * 64];
    __shared__ unsigned short lsB[128 * 64];
    const int blk = blockIdx.x;
    const int m0 = (blk >> 3) * 128;   // f
    const int n0 = (blk & 7) * 128;    // e
    const int K = 1024;
    GEMM_DECLS
    f32x4 acc[4][4] = {};
    GEMM_KLOOP(Wkt, Wqt, 1024, 1024)
#pragma unroll
    for (int j = 0; j < 4; ++j) {
        const int n = n0 + wn + j * 16 + lr;
#pragma unroll
        for (int i = 0; i < 4; ++i) {
            const int mbase = m0 + wm + i * 16 + quad * 4;
#pragma unroll
            for (int r = 0; r < 4; ++r)
                Mt[(long)(mbase + r) * 1024 + n] = f2bf(acc[i][j][r]);
        }
    }
}

// tv: ids [0,1024): GEMM z=0 -> T = X.M (bf16, d_out), z=1 -> V -> Vt transposed.
// ids [1024,1088): u/w matvec waves (u = X.g1 ; w = X.g2 + c), 256 waves x 64 rows.
__global__ __launch_bounds__(256, 2)
void gemm_tv(const unsigned short* __restrict__ Xb,
             const unsigned short* __restrict__ Mt,
             const unsigned short* __restrict__ Wvb,
             const float* __restrict__ bv_,
             const float* __restrict__ g1, const float* __restrict__ g2,
             const float* __restrict__ cbuf,
             unsigned short* __restrict__ T, unsigned short* __restrict__ Vt,
             float* __restrict__ u, float* __restrict__ w)
{
    __shared__ unsigned short lsA[128 * 64];
    __shared__ unsigned short lsB[128 * 64];
    const int id = blockIdx.x;

    if (id >= 1024) {                         // u/w matvec
        const int t = threadIdx.x;
        const int wave = t >> 6, lane = t & 63;
        const int wid = (id - 1024) * 4 + wave;          // 0..255
        const float* g = (wid < 128) ? g1 : g2;
        const float4* gf = reinterpret_cast<const float4*>(g);
        float4 q0 = gf[lane * 2], q1 = gf[lane * 2 + 1];
        float4 q2 = gf[128 + lane * 2], q3 = gf[128 + lane * 2 + 1];
        const float cadd = (wid < 128) ? 0.0f : *cbuf;
        for (int rr = 0; rr < 64; ++rr) {
            const int row  = wid * 64 + rr;              // 0..16383
            const int xrow = row & 8191;
            uint4 x0 = *reinterpret_cast<const uint4*>(Xb + (long)xrow * 1024 + lane * 8);
            uint4 x1 = *reinterpret_cast<const uint4*>(Xb + (long)xrow * 1024 + 512 + lane * 8);
            float s = wave_reduce(dot8(x0, q0, q1) + dot8(x1, q2, q3));
            if (lane == 0) {
                if (row < 8192) u[row] = s;
                else            w[row - 8192] = s + cadd;
            }
        }
        return;
    }

    const int g   = id & 7;
    const int jj  = id >> 3;
    const int xx  = jj & 7;
    const int yin = (jj >> 3) & 7;
    const int z   = jj >> 6;                  // 0=T, 1=V

    const unsigned short* B = (z == 0) ? Mt : Wvb;
    const int n0 = xx * 128;
    const int m0 = (g * 8 + yin) * 128;
    const int K = 1024;

    GEMM_DECLS
    f32x4 acc[4][4] = {};
    GEMM_KLOOP(Xb, B, 1024, 1024)

#pragma unroll
    for (int j = 0; j < 4; ++j) {
        const int n = n0 + wn + j * 16 + lr;
        const float bvv = (z == 1) ? bv_[n] : 0.0f;
#pragma unroll
        for (int i = 0; i < 4; ++i) {
            const int mbase = m0 + wm + i * 16 + quad * 4;
            if (z == 0) {
#pragma unroll
                for (int r = 0; r < 4; ++r)
                    T[(long)(mbase + r) * 1024 + n] = f2bf(acc[i][j][r]);
            } else {
                ushort4 o;
                o.x = f2bf(acc[i][j][0] + bvv);
                o.y = f2bf(acc[i][j][1] + bvv);
                o.z = f2bf(acc[i][j][2] + bvv);
                o.w = f2bf(acc[i][j][3] + bvv);
                long boff = (long)(mbase >> 11) * (1024L * 2048) + (long)n * 2048 + (mbase & 2047);
                *reinterpret_cast<ushort4*>(Vt + boff) = o;
            }
        }
    }
}

// Scores: P[b][j][i] = exp((T_j.X_i + u_j + w_i)*scale) bf16, l atomics.
__global__ __launch_bounds__(256, 2)
void gemm_scores(const unsigned short* __restrict__ T,
                 const unsigned short* __restrict__ Xb,
                 const float* __restrict__ u, const float* __restrict__ w,
                 unsigned short* __restrict__ P, float* __restrict__ l,
                 float scale)
{
    __shared__ unsigned short lsA[128 * 64];
    __shared__ unsigned short lsB[128 * 64];

    const int id  = blockIdx.x;
    const int g   = id & 7;
    const int uu  = id >> 3;
    const int bz  = g >> 1;
    const int mh  = g & 1;
    const int yin = uu & 7;
    const int xx  = uu >> 3;                 // 0..15

    const unsigned short* A = T  + (long)bz * 2048 * 1024;
    const unsigned short* B = Xb + (long)bz * 2048 * 1024;
    unsigned short* Pb = P + (long)bz * 2048 * 2048;
    float* lb = l + bz * 2048;

    const int n0 = xx * 128;
    const int m0 = (mh * 8 + yin) * 128;
    const int K = 1024;

    GEMM_DECLS
    f32x4 acc[4][4] = {};
    GEMM_KLOOP(A, B, 1024, 1024)

    float wn4[4];
#pragma unroll
    for (int j = 0; j < 4; ++j)
        wn4[j] = w[bz * 2048 + n0 + wn + j * 16 + lr];

#pragma unroll
    for (int i = 0; i < 4; ++i) {
#pragma unroll
        for (int r = 0; r < 4; ++r) {
            const int m = m0 + wm + i * 16 + quad * 4 + r;
            const float um = u[bz * 2048 + m];
            float psum = 0.0f;
#pragma unroll
            for (int j = 0; j < 4; ++j) {
                const float p = __expf((acc[i][j][r] + um + wn4[j]) * scale);
                psum += p;
                const int n = n0 + wn + j * 16 + lr;
                Pb[(long)m * 2048 + n] = f2bf(p);
            }
#pragma unroll
            for (int o = 1; o < 16; o <<= 1) psum += __shfl_xor(psum, o, 64);
            if (lr == 0) atomicAdd(&lb[m], psum);
        }
    }
}

// Y[b][j][d] = (1/l[b,j]) * sum_i P[b][j][i]*Vt[b][d][i] -> fp32 out.
__global__ __launch_bounds__(256, 2)
void gemm_y(const unsigned short* __restrict__ P,
            const unsigned short* __restrict__ Vt,
            const float* __restrict__ l, float* __restrict__ out)
{
    __shared__ unsigned short lsA[128 * 64];
    __shared__ unsigned short lsB[128 * 64];

    const int id  = blockIdx.x;
    const int g   = id & 7;
    const int uu  = id >> 3;
    const int bz  = g >> 1;
    const int mh  = g & 1;
    const int yin = uu & 7;
    const int xx  = uu >> 3;                 // 0..7

    const unsigned short* A = P  + (long)bz * 2048 * 2048;
    const unsigned short* B = Vt + (long)bz * 1024 * 2048;
    const float* lb = l + bz * 2048;
    float* C = out + (long)bz * 2048 * 1024;

    const int n0 = xx * 128;
    const int m0 = (mh * 8 + yin) * 128;
    const int K = 2048;

    GEMM_DECLS
    f32x4 acc[4][4] = {};
    GEMM_KLOOP(A, B, 2048, 2048)

    float linv[4][4];
#pragma unroll
    for (int i = 0; i < 4; ++i)
#pragma unroll
        for (int r = 0; r < 4; ++r)
            linv[i][r] = 1.0f / lb[m0 + wm + i * 16 + quad * 4 + r];

#pragma unroll
    for (int j = 0; j < 4; ++j) {
        const int n = n0 + wn + j * 16 + lr;
#pragma unroll
        for (int i = 0; i < 4; ++i) {
            const int mbase = m0 + wm + i * 16 + quad * 4;
#pragma unroll
            for (int r = 0; r < 4; ++r)
                C[(long)(mbase + r) * 1024 + n] = acc[i][j][r] * linv[i][r];
        }
    }
}

extern "C" void kernel_launch(void* const* d_in, const int* in_sizes, int n_in,
                              void* d_out, int out_size, void* d_ws, size_t ws_size,
                              hipStream_t stream) {
    const float* X  = (const float*)d_in[0];
    const float* Wk = (const float*)d_in[1];
    const float* bk = (const float*)d_in[2];
    const float* Wq = (const float*)d_in[3];
    const float* bq = (const float*)d_in[4];
    const float* Wv = (const float*)d_in[5];
    const float* bv = (const float*)d_in[6];
    float* out = (float*)d_out;

    const size_t MB = 1024 * 1024;
    if (ws_size < 80 * MB) return;   // visible failure instead of OOB corruption

    char* ws = (char*)d_ws;
    unsigned short* Vt  = (unsigned short*)(ws);            // 16 MiB
    unsigned short* P   = (unsigned short*)(ws + 16 * MB);  // 32 MiB
    unsigned short* Xbf = (unsigned short*)(ws + 48 * MB);  // 16 MiB
    unsigned short* Wqt = (unsigned short*)(ws + 64 * MB);  // 2 MiB (transposed)
    unsigned short* Wkt = (unsigned short*)(ws + 66 * MB);  // 2 MiB (transposed)
    unsigned short* Wvb = (unsigned short*)(ws + 68 * MB);  // 2 MiB
    unsigned short* Mt  = (unsigned short*)(ws + 70 * MB);  // 2 MiB
    float* l    = (float*)(ws + 72 * MB);                   // 32 KiB
    float* u    = (float*)(ws + 72 * MB + 32 * 1024);       // 32 KiB
    float* w    = (float*)(ws + 72 * MB + 64 * 1024);       // 32 KiB
    float* g1   = (float*)(ws + 72 * MB + 96 * 1024);       // 4 KiB
    float* g2   = (float*)(ws + 72 * MB + 100 * 1024);      // 4 KiB
    float* cbuf = (float*)(ws + 72 * MB + 104 * 1024);      // 4 B
    // T bf16 (16 MiB) lives in d_out until gemm_y overwrites it
    unsigned short* T = (unsigned short*)d_out;

    dim3 blk(256);

    // 1) cvt: X, Wv plain; Wq/Wk transposed; g1/g2/c; zero l
    cvt_all<<<9737, blk, 0, stream>>>(X, Wq, Wk, Wv, bq, bk,
                                      Xbf, Wqt, Wkt, Wvb, g1, g2, cbuf, l);

    // 2) Mt = Wq^T.Wk (stored [f][e]), 64 blocks
    aux_k<<<64, blk, 0, stream>>>(Wkt, Wqt, Mt);

    // 3) T = X.M, V -> Vt; u,w matvecs
    gemm_tv<<<1088, blk, 0, stream>>>(Xbf, Mt, Wvb, bv, g1, g2, cbuf, T, Vt, u, w);

    // 4) scores + exp + row-sum atomics
    gemm_scores<<<1024, blk, 0, stream>>>(T, Xbf, u, w, P, l, 0.022097086912079608f);

    // 5) Y = (P @ Vt^T) / l
    gemm_y<<<512, blk, 0, stream>>>(P, Vt, l, out);
}